// Round 19
// baseline (308.855 us; speedup 1.0000x reference)
//
#include <hip/hip_runtime.h>
#include <math.h>

#define NDIM 128

// ONE WAVE = ONE BATCH (64-thread blocks, grid = 4096). Round-18 kernel
// (89us: qx recurrence eliminates outer matvec; Eisenstat-Walker forcing;
// DPP reductions; zero barriers) with ONE change: __launch_bounds__(64,4).
//
// Round-18 model: launch_bounds(64,2) left only ~8 blocks/CU resident ->
// the 16-blocks/CU grid ran as TWO sequential (stage+compute) rounds
// (~2x21us staging + 2x20us compute ~ 85us = measured 89us). VGPR=124 fits
// the 4-waves/EU budget (128), so declaring min 4 waves/EU makes the whole
// grid co-resident: ONE HBM-bound staging burst overlapped across all
// waves, then one fully-parallel compute phase. No other change.
//
// Carried: lane owns rows r0=2*lane,r0+1 as 128 named u32 packed fp16 RTN
// (VGPR-resident); Q global read EXACTLY once; qx maintained by CG-exit
// recurrence Qh*dku = u - umax*rs - ex.*dku (same Qh operator -> same fixed
// point); eta = clamp(lk,0.01,0.3), rztol = eta^2; exit lk < 1e-4.
// absmax floor 1.22e-4 = fp16-Q operator error (threshold 4.17e-4).

typedef __fp16 h2_t __attribute__((ext_vector_type(2)));
union U32H2 { unsigned int u; h2_t h; };

#if __has_builtin(__builtin_amdgcn_fdot2)
#define FDOT2(a,b,c) __builtin_amdgcn_fdot2((a),(b),(c),false)
#else
#define FDOT2(a,b,c) fmaf((float)(a).x,(float)(b).x, fmaf((float)(a).y,(float)(b).y,(c)))
#endif

__device__ __forceinline__ unsigned int pk_rtn(float x, float y) {
    U32H2 r; r.h.x = (__fp16)x; r.h.y = (__fp16)y; return r.u;   // RTN converts
}

#define DOTG(qu, vu, ACC) { U32H2 _q, _v; _q.u = (qu); _v.u = (vu);            \
    ACC = FDOT2(_q.h, _v.h, ACC); }

// ---- DPP wave64 reductions (VALU pipe; bound_ctrl=true -> OOB reads give 0) ----
template<int CTRL>
__device__ __forceinline__ float dppadd(float v) {
    const int t = __builtin_amdgcn_update_dpp(0, __float_as_int(v), CTRL, 0xf, 0xf, true);
    return v + __int_as_float(t);
}
template<int CTRL>
__device__ __forceinline__ float dppmax(float v) {   // valid for v >= 0 (OOB gives 0)
    const int t = __builtin_amdgcn_update_dpp(0, __float_as_int(v), CTRL, 0xf, 0xf, true);
    return fmaxf(v, __int_as_float(t));
}
// row_shr:1=0x111 :2=0x112 :4=0x114 :8=0x118, row_bcast15=0x142, row_bcast31=0x143
#define WSUM(v) { v=dppadd<0x111>(v); v=dppadd<0x112>(v); v=dppadd<0x114>(v);  \
                  v=dppadd<0x118>(v); v=dppadd<0x142>(v); v=dppadd<0x143>(v);  \
                  v=__int_as_float(__builtin_amdgcn_readlane(__float_as_int(v),63)); }
#define WMAX(v) { v=dppmax<0x111>(v); v=dppmax<0x112>(v); v=dppmax<0x114>(v);  \
                  v=dppmax<0x118>(v); v=dppmax<0x142>(v); v=dppmax<0x143>(v);  \
                  v=__int_as_float(__builtin_amdgcn_readlane(__float_as_int(v),63)); }

__global__ __launch_bounds__(64, 4)
void rpth_kernel(const float* __restrict__ Q,
                 const float* __restrict__ R,
                 float* __restrict__ out)
{
    const int b    = blockIdx.x;
    const int lane = threadIdx.x;            // 0..63
    const int r0   = 2 * lane;

    __shared__ __align__(16) unsigned int s_v [64];   // packed CG vector
    __shared__ __align__(16) unsigned int s_xh[64];   // packed x0 hi (it=0 only)
    __shared__ __align__(16) unsigned int s_xl[64];   // packed x0 lo (it=0 only)

    const size_t qbase = (size_t)b * (NDIM * NDIM);
    const float* p0 = Q + qbase + (size_t)r0 * NDIM;
    const float* p1 = p0 + NDIM;

    // ---- 128 named u32 scalars: packed fp16 Q rows r0 (a*) and r0+1 (b*) ----
#define DECL(c) unsigned a##c##_0,a##c##_1,a##c##_2,a##c##_3,                  \
                         b##c##_0,b##c##_1,b##c##_2,b##c##_3;
    DECL(0)  DECL(1)  DECL(2)  DECL(3)  DECL(4)  DECL(5)  DECL(6)  DECL(7)
    DECL(8)  DECL(9)  DECL(10) DECL(11) DECL(12) DECL(13) DECL(14) DECL(15)
#undef DECL
#define STG(c) {                                                               \
    const float4 _x0 = ((const float4*)p0)[2*(c)];                             \
    const float4 _x1 = ((const float4*)p0)[2*(c)+1];                           \
    const float4 _y0 = ((const float4*)p1)[2*(c)];                             \
    const float4 _y1 = ((const float4*)p1)[2*(c)+1];                           \
    a##c##_0 = pk_rtn(_x0.x,_x0.y); a##c##_1 = pk_rtn(_x0.z,_x0.w);            \
    a##c##_2 = pk_rtn(_x1.x,_x1.y); a##c##_3 = pk_rtn(_x1.z,_x1.w);            \
    b##c##_0 = pk_rtn(_y0.x,_y0.y); b##c##_1 = pk_rtn(_y0.z,_y0.w);            \
    b##c##_2 = pk_rtn(_y1.x,_y1.y); b##c##_3 = pk_rtn(_y1.z,_y1.w); }
    STG(0)  STG(1)  STG(2)  STG(3)  STG(4)  STG(5)  STG(6)  STG(7)
    STG(8)  STG(9)  STG(10) STG(11) STG(12) STG(13) STG(14) STG(15)
#undef STG

    const float qd0 = Q[qbase + (size_t)r0 * (NDIM + 1)];
    const float qd1 = Q[qbase + (size_t)(r0 + 1) * (NDIM + 1)];
    const float2 rr = ((const float2*)(R + (size_t)b * NDIM))[lane];
    const float rv0 = fabsf(rr.x), rv1 = fabsf(rr.y);

    float xv0 = rv0 / sqrtf(qd0);            // x0 = r / sqrt(diag Q)
    float xv1 = rv1 / sqrtf(qd1);

    const float FLc = 0.36286771f;           // 0.95*(3-sqrt(5))/2
    float lk = FLc + 1.0f;

    // ---- one-time publish of x0 (hi/lo) and one-time outer matvec Qh*x0 ----
    {
        const float _h0 = (float)(__fp16)xv0, _h1 = (float)(__fp16)xv1;
        s_xh[lane] = pk_rtn(xv0, xv1);
        s_xl[lane] = pk_rtn((xv0 - _h0) * 1024.f, (xv1 - _h1) * 1024.f);
        asm volatile("" ::: "memory");
    }
    const uint4* vhp = (const uint4*)s_xh;
    const uint4* vlp = (const uint4*)s_xl;
    const uint4* vp  = (const uint4*)s_v;

    float qx0, qx1;
    {
        float ah0=0.f, ah1=0.f, al0=0.f, al1=0.f;
#define MVO(c) { const uint4 _Vh = vhp[c], _Vl = vlp[c];                       \
    DOTG(a##c##_0,_Vh.x,ah0) DOTG(a##c##_1,_Vh.y,ah0)                          \
    DOTG(a##c##_2,_Vh.z,ah0) DOTG(a##c##_3,_Vh.w,ah0)                          \
    DOTG(b##c##_0,_Vh.x,ah1) DOTG(b##c##_1,_Vh.y,ah1)                          \
    DOTG(b##c##_2,_Vh.z,ah1) DOTG(b##c##_3,_Vh.w,ah1)                          \
    DOTG(a##c##_0,_Vl.x,al0) DOTG(a##c##_1,_Vl.y,al0)                          \
    DOTG(a##c##_2,_Vl.z,al0) DOTG(a##c##_3,_Vl.w,al0)                          \
    DOTG(b##c##_0,_Vl.x,al1) DOTG(b##c##_1,_Vl.y,al1)                          \
    DOTG(b##c##_2,_Vl.z,al1) DOTG(b##c##_3,_Vl.w,al1) }
        MVO(0)  MVO(1)  MVO(2)  MVO(3)  MVO(4)  MVO(5)  MVO(6)  MVO(7)
        MVO(8)  MVO(9)  MVO(10) MVO(11) MVO(12) MVO(13) MVO(14) MVO(15)
#undef MVO
        qx0 = fmaf(al0, 9.765625e-4f, ah0);
        qx1 = fmaf(al1, 9.765625e-4f, ah1);
    }

    for (int it = 0; it < 10; ++it) {
        const float rx0 = rv0 / xv0,  rx1 = rv1 / xv1;
        const float u0  = qx0 - rx0,  u1  = qx1 - rx1;    // u = Qh x - r/x
        const float ex0 = rx0 / xv0,  ex1 = rx1 / xv1;    // r/x^2
        const float ih0 = 1.0f / (qd0 + ex0);             // Jacobi precond
        const float ih1 = 1.0f / (qd1 + ex1);

        float umax = fmaxf(fabsf(u0), fabsf(u1));
        WMAX(umax);
        const float sigma = 1.0f / fmaxf(umax, 1e-30f);

        // Eisenstat-Walker forcing: loose early (damped steps), tight late
        const float eta   = fminf(0.3f, fmaxf(0.01f, lk));
        const float rztol = eta * eta;

        // ---- Chronopoulos-Gear PCG on h = Qh + diag(ex), scaled RHS ----
        float rs0 = u0 * sigma, rs1 = u1 * sigma;
        float z0  = rs0 * ih0,  z1  = rs1 * ih1;
        float dk0 = 0.f, dk1 = 0.f, pp0 = 0.f, pp1 = 0.f, sa0 = 0.f, sa1 = 0.f;
        float alpha = 1.f, rzp = 1.f, rz0v = 0.f;
        s_v[lane] = pk_rtn(z0, z1);
        asm volatile("" ::: "memory");

        for (int cg = 0; cg < 16; ++cg) {
            float ac0a=0.f, ac0b=0.f, ac1a=0.f, ac1b=0.f;
#define MVI(c,X0,X1) { const uint4 _V = vp[c];                                 \
    DOTG(a##c##_0,_V.x,X0) DOTG(a##c##_1,_V.y,X0)                              \
    DOTG(a##c##_2,_V.z,X0) DOTG(a##c##_3,_V.w,X0)                              \
    DOTG(b##c##_0,_V.x,X1) DOTG(b##c##_1,_V.y,X1)                              \
    DOTG(b##c##_2,_V.z,X1) DOTG(b##c##_3,_V.w,X1) }
            MVI(0,ac0a,ac1a)  MVI(1,ac0b,ac1b)  MVI(2,ac0a,ac1a)  MVI(3,ac0b,ac1b)
            MVI(4,ac0a,ac1a)  MVI(5,ac0b,ac1b)  MVI(6,ac0a,ac1a)  MVI(7,ac0b,ac1b)
            MVI(8,ac0a,ac1a)  MVI(9,ac0b,ac1b)  MVI(10,ac0a,ac1a) MVI(11,ac0b,ac1b)
            MVI(12,ac0a,ac1a) MVI(13,ac0b,ac1b) MVI(14,ac0a,ac1a) MVI(15,ac0b,ac1b)
#undef MVI
            const float w0 = fmaf(ex0, z0, ac0a + ac0b);  // h z
            const float w1 = fmaf(ex1, z1, ac1a + ac1b);

            float pr = fmaf(rs0, z0, rs1 * z1);      // rz
            float pd = fmaf(z0,  w0, z1  * w1);      // z.hz
            WSUM(pr); WSUM(pd);
            if (cg == 0) { rz0v = pr; if (rz0v <= 1e-30f) break; }
            else if (pr <= rztol * rz0v || pr <= 1e-32f) break;   // EW tol
            const float beta = (cg == 0) ? 0.0f : pr / rzp;
            const float pAp  = pd - beta * pr / alpha;
            alpha = pr / pAp;
            pp0 = fmaf(beta, pp0, z0);  pp1 = fmaf(beta, pp1, z1);
            sa0 = fmaf(beta, sa0, w0);  sa1 = fmaf(beta, sa1, w1);   // h p
            dk0 = fmaf(alpha, pp0, dk0); dk1 = fmaf(alpha, pp1, dk1);
            rs0 = fmaf(-alpha, sa0, rs0); rs1 = fmaf(-alpha, sa1, rs1);
            z0 = rs0 * ih0;  z1 = rs1 * ih1;
            rzp = pr;
            s_v[lane] = pk_rtn(z0, z1);              // republish
            asm volatile("" ::: "memory");
        }
        const float dku0 = dk0 * umax, dku1 = dk1 * umax;   // unscale

        // ---- damping / bookkeeping (exact reference logic, fp32) ----
        float gp = fmaxf(fabsf(dku0 / xv0), fabsf(dku1 / xv1));
        float sp = fmaf(dku0, u0, dku1 * u1);
        WMAX(gp); WSUM(sp);
        const float gk     = (lk <= FLc) ? 0.0f : gp;
        const float lk_new = sqrtf(fmaxf(sp, 0.0f));
        const float damp   = 1.0f / (1.0f + gk);
        xv0 -= dku0 * damp;
        xv1 -= dku1 * damp;
        // ---- qx recurrence: Qh*dku = u - umax*rs - ex.*dku (CG invariant) ----
        qx0 -= damp * (u0 - umax * rs0 - ex0 * dku0);
        qx1 -= damp * (u1 - umax * rs1 - ex1 * dku1);
        lk = lk_new;
        if (lk_new < 1e-4f) break;     // remaining motion <= 1e-4 -> out ~4e-6
    }

    // ---- normalize: x / (sum|x| + 1e-8) ----
    float sab = fabsf(xv0) + fabsf(xv1);
    WSUM(sab);
    const float inv = 1.0f / (sab + 1e-8f);
    ((float2*)(out + (size_t)b * NDIM))[lane] = make_float2(xv0 * inv, xv1 * inv);
}

extern "C" void kernel_launch(void* const* d_in, const int* in_sizes, int n_in,
                              void* d_out, int out_size, void* d_ws, size_t ws_size,
                              hipStream_t stream) {
    const float* Q = (const float*)d_in[0];
    const float* R = (const float*)d_in[1];
    float* out     = (float*)d_out;
    const int B    = in_sizes[1] / NDIM;   // 4096
    rpth_kernel<<<dim3(B), dim3(64), 0, stream>>>(Q, R, out);
}

// Round 20
// 88.721 us; speedup vs baseline: 3.4812x; 3.4812x over previous
//
#include <hip/hip_runtime.h>
#include <math.h>

#define NDIM 128

// ONE WAVE = ONE BATCH (64-thread blocks, grid = 4096). EXACT REVERT to the
// round-18 kernel (89us) -- the proven optimum.
//
// Round-19 lesson (confirming rounds 11/12): __launch_bounds__' 2nd arg is a
// COMPILER ALLOCATION TARGET, not a HW residency limit. Declaring (64,4)
// capped VGPRs at 64 and spilled all Q to scratch (WRITE 2->118 MB, FETCH
// 172->491 MB, 309us). At (64,2) the allocator gives VGPR=124, and the
// HARDWARE already schedules 4 waves/SIMD at 124 regs -> grid fully
// co-resident. (64,2) is the sweet spot; do not touch.
//
// Structure: lane owns rows r0=2*lane,r0+1 as 128 named u32 packed fp16 RTN
// (VGPR-resident; no arrays/aggregates/pins -- any address-taken form goes
// to scratch); zero __syncthreads; DPP row_shr/row_bcast reductions (VALU
// pipe); CG vector published in LDS (wave-synchronous ds ordering via asm
// clobber); Q global read EXACTLY once.
// Algorithm: damped Newton (exact reference lk/gk logic) with qx maintained
// by the CG-exit recurrence Qh*dku = u - umax*rs - ex.*dku (same Qh operator
// -> same fixed point; outer matvec only at it=0); inner Jacobi-
// preconditioned Chronopoulos-Gear CG with Eisenstat-Walker forcing
// eta = clamp(lk, 0.01, 0.3), rztol = eta^2; per-batch exit lk < 1e-4.
// absmax floor 1.22e-4 = fp16-Q operator error (threshold 4.17e-4).

typedef __fp16 h2_t __attribute__((ext_vector_type(2)));
union U32H2 { unsigned int u; h2_t h; };

#if __has_builtin(__builtin_amdgcn_fdot2)
#define FDOT2(a,b,c) __builtin_amdgcn_fdot2((a),(b),(c),false)
#else
#define FDOT2(a,b,c) fmaf((float)(a).x,(float)(b).x, fmaf((float)(a).y,(float)(b).y,(c)))
#endif

__device__ __forceinline__ unsigned int pk_rtn(float x, float y) {
    U32H2 r; r.h.x = (__fp16)x; r.h.y = (__fp16)y; return r.u;   // RTN converts
}

#define DOTG(qu, vu, ACC) { U32H2 _q, _v; _q.u = (qu); _v.u = (vu);            \
    ACC = FDOT2(_q.h, _v.h, ACC); }

// ---- DPP wave64 reductions (VALU pipe; bound_ctrl=true -> OOB reads give 0) ----
template<int CTRL>
__device__ __forceinline__ float dppadd(float v) {
    const int t = __builtin_amdgcn_update_dpp(0, __float_as_int(v), CTRL, 0xf, 0xf, true);
    return v + __int_as_float(t);
}
template<int CTRL>
__device__ __forceinline__ float dppmax(float v) {   // valid for v >= 0 (OOB gives 0)
    const int t = __builtin_amdgcn_update_dpp(0, __float_as_int(v), CTRL, 0xf, 0xf, true);
    return fmaxf(v, __int_as_float(t));
}
// row_shr:1=0x111 :2=0x112 :4=0x114 :8=0x118, row_bcast15=0x142, row_bcast31=0x143
#define WSUM(v) { v=dppadd<0x111>(v); v=dppadd<0x112>(v); v=dppadd<0x114>(v);  \
                  v=dppadd<0x118>(v); v=dppadd<0x142>(v); v=dppadd<0x143>(v);  \
                  v=__int_as_float(__builtin_amdgcn_readlane(__float_as_int(v),63)); }
#define WMAX(v) { v=dppmax<0x111>(v); v=dppmax<0x112>(v); v=dppmax<0x114>(v);  \
                  v=dppmax<0x118>(v); v=dppmax<0x142>(v); v=dppmax<0x143>(v);  \
                  v=__int_as_float(__builtin_amdgcn_readlane(__float_as_int(v),63)); }

__global__ __launch_bounds__(64, 2)
void rpth_kernel(const float* __restrict__ Q,
                 const float* __restrict__ R,
                 float* __restrict__ out)
{
    const int b    = blockIdx.x;
    const int lane = threadIdx.x;            // 0..63
    const int r0   = 2 * lane;

    __shared__ __align__(16) unsigned int s_v [64];   // packed CG vector
    __shared__ __align__(16) unsigned int s_xh[64];   // packed x0 hi (it=0 only)
    __shared__ __align__(16) unsigned int s_xl[64];   // packed x0 lo (it=0 only)

    const size_t qbase = (size_t)b * (NDIM * NDIM);
    const float* p0 = Q + qbase + (size_t)r0 * NDIM;
    const float* p1 = p0 + NDIM;

    // ---- 128 named u32 scalars: packed fp16 Q rows r0 (a*) and r0+1 (b*) ----
#define DECL(c) unsigned a##c##_0,a##c##_1,a##c##_2,a##c##_3,                  \
                         b##c##_0,b##c##_1,b##c##_2,b##c##_3;
    DECL(0)  DECL(1)  DECL(2)  DECL(3)  DECL(4)  DECL(5)  DECL(6)  DECL(7)
    DECL(8)  DECL(9)  DECL(10) DECL(11) DECL(12) DECL(13) DECL(14) DECL(15)
#undef DECL
#define STG(c) {                                                               \
    const float4 _x0 = ((const float4*)p0)[2*(c)];                             \
    const float4 _x1 = ((const float4*)p0)[2*(c)+1];                           \
    const float4 _y0 = ((const float4*)p1)[2*(c)];                             \
    const float4 _y1 = ((const float4*)p1)[2*(c)+1];                           \
    a##c##_0 = pk_rtn(_x0.x,_x0.y); a##c##_1 = pk_rtn(_x0.z,_x0.w);            \
    a##c##_2 = pk_rtn(_x1.x,_x1.y); a##c##_3 = pk_rtn(_x1.z,_x1.w);            \
    b##c##_0 = pk_rtn(_y0.x,_y0.y); b##c##_1 = pk_rtn(_y0.z,_y0.w);            \
    b##c##_2 = pk_rtn(_y1.x,_y1.y); b##c##_3 = pk_rtn(_y1.z,_y1.w); }
    STG(0)  STG(1)  STG(2)  STG(3)  STG(4)  STG(5)  STG(6)  STG(7)
    STG(8)  STG(9)  STG(10) STG(11) STG(12) STG(13) STG(14) STG(15)
#undef STG

    const float qd0 = Q[qbase + (size_t)r0 * (NDIM + 1)];
    const float qd1 = Q[qbase + (size_t)(r0 + 1) * (NDIM + 1)];
    const float2 rr = ((const float2*)(R + (size_t)b * NDIM))[lane];
    const float rv0 = fabsf(rr.x), rv1 = fabsf(rr.y);

    float xv0 = rv0 / sqrtf(qd0);            // x0 = r / sqrt(diag Q)
    float xv1 = rv1 / sqrtf(qd1);

    const float FLc = 0.36286771f;           // 0.95*(3-sqrt(5))/2
    float lk = FLc + 1.0f;

    // ---- one-time publish of x0 (hi/lo) and one-time outer matvec Qh*x0 ----
    {
        const float _h0 = (float)(__fp16)xv0, _h1 = (float)(__fp16)xv1;
        s_xh[lane] = pk_rtn(xv0, xv1);
        s_xl[lane] = pk_rtn((xv0 - _h0) * 1024.f, (xv1 - _h1) * 1024.f);
        asm volatile("" ::: "memory");
    }
    const uint4* vhp = (const uint4*)s_xh;
    const uint4* vlp = (const uint4*)s_xl;
    const uint4* vp  = (const uint4*)s_v;

    float qx0, qx1;
    {
        float ah0=0.f, ah1=0.f, al0=0.f, al1=0.f;
#define MVO(c) { const uint4 _Vh = vhp[c], _Vl = vlp[c];                       \
    DOTG(a##c##_0,_Vh.x,ah0) DOTG(a##c##_1,_Vh.y,ah0)                          \
    DOTG(a##c##_2,_Vh.z,ah0) DOTG(a##c##_3,_Vh.w,ah0)                          \
    DOTG(b##c##_0,_Vh.x,ah1) DOTG(b##c##_1,_Vh.y,ah1)                          \
    DOTG(b##c##_2,_Vh.z,ah1) DOTG(b##c##_3,_Vh.w,ah1)                          \
    DOTG(a##c##_0,_Vl.x,al0) DOTG(a##c##_1,_Vl.y,al0)                          \
    DOTG(a##c##_2,_Vl.z,al0) DOTG(a##c##_3,_Vl.w,al0)                          \
    DOTG(b##c##_0,_Vl.x,al1) DOTG(b##c##_1,_Vl.y,al1)                          \
    DOTG(b##c##_2,_Vl.z,al1) DOTG(b##c##_3,_Vl.w,al1) }
        MVO(0)  MVO(1)  MVO(2)  MVO(3)  MVO(4)  MVO(5)  MVO(6)  MVO(7)
        MVO(8)  MVO(9)  MVO(10) MVO(11) MVO(12) MVO(13) MVO(14) MVO(15)
#undef MVO
        qx0 = fmaf(al0, 9.765625e-4f, ah0);
        qx1 = fmaf(al1, 9.765625e-4f, ah1);
    }

    for (int it = 0; it < 10; ++it) {
        const float rx0 = rv0 / xv0,  rx1 = rv1 / xv1;
        const float u0  = qx0 - rx0,  u1  = qx1 - rx1;    // u = Qh x - r/x
        const float ex0 = rx0 / xv0,  ex1 = rx1 / xv1;    // r/x^2
        const float ih0 = 1.0f / (qd0 + ex0);             // Jacobi precond
        const float ih1 = 1.0f / (qd1 + ex1);

        float umax = fmaxf(fabsf(u0), fabsf(u1));
        WMAX(umax);
        const float sigma = 1.0f / fmaxf(umax, 1e-30f);

        // Eisenstat-Walker forcing: loose early (damped steps), tight late
        const float eta   = fminf(0.3f, fmaxf(0.01f, lk));
        const float rztol = eta * eta;

        // ---- Chronopoulos-Gear PCG on h = Qh + diag(ex), scaled RHS ----
        float rs0 = u0 * sigma, rs1 = u1 * sigma;
        float z0  = rs0 * ih0,  z1  = rs1 * ih1;
        float dk0 = 0.f, dk1 = 0.f, pp0 = 0.f, pp1 = 0.f, sa0 = 0.f, sa1 = 0.f;
        float alpha = 1.f, rzp = 1.f, rz0v = 0.f;
        s_v[lane] = pk_rtn(z0, z1);
        asm volatile("" ::: "memory");

        for (int cg = 0; cg < 16; ++cg) {
            float ac0a=0.f, ac0b=0.f, ac1a=0.f, ac1b=0.f;
#define MVI(c,X0,X1) { const uint4 _V = vp[c];                                 \
    DOTG(a##c##_0,_V.x,X0) DOTG(a##c##_1,_V.y,X0)                              \
    DOTG(a##c##_2,_V.z,X0) DOTG(a##c##_3,_V.w,X0)                              \
    DOTG(b##c##_0,_V.x,X1) DOTG(b##c##_1,_V.y,X1)                              \
    DOTG(b##c##_2,_V.z,X1) DOTG(b##c##_3,_V.w,X1) }
            MVI(0,ac0a,ac1a)  MVI(1,ac0b,ac1b)  MVI(2,ac0a,ac1a)  MVI(3,ac0b,ac1b)
            MVI(4,ac0a,ac1a)  MVI(5,ac0b,ac1b)  MVI(6,ac0a,ac1a)  MVI(7,ac0b,ac1b)
            MVI(8,ac0a,ac1a)  MVI(9,ac0b,ac1b)  MVI(10,ac0a,ac1a) MVI(11,ac0b,ac1b)
            MVI(12,ac0a,ac1a) MVI(13,ac0b,ac1b) MVI(14,ac0a,ac1a) MVI(15,ac0b,ac1b)
#undef MVI
            const float w0 = fmaf(ex0, z0, ac0a + ac0b);  // h z
            const float w1 = fmaf(ex1, z1, ac1a + ac1b);

            float pr = fmaf(rs0, z0, rs1 * z1);      // rz
            float pd = fmaf(z0,  w0, z1  * w1);      // z.hz
            WSUM(pr); WSUM(pd);
            if (cg == 0) { rz0v = pr; if (rz0v <= 1e-30f) break; }
            else if (pr <= rztol * rz0v || pr <= 1e-32f) break;   // EW tol
            const float beta = (cg == 0) ? 0.0f : pr / rzp;
            const float pAp  = pd - beta * pr / alpha;
            alpha = pr / pAp;
            pp0 = fmaf(beta, pp0, z0);  pp1 = fmaf(beta, pp1, z1);
            sa0 = fmaf(beta, sa0, w0);  sa1 = fmaf(beta, sa1, w1);   // h p
            dk0 = fmaf(alpha, pp0, dk0); dk1 = fmaf(alpha, pp1, dk1);
            rs0 = fmaf(-alpha, sa0, rs0); rs1 = fmaf(-alpha, sa1, rs1);
            z0 = rs0 * ih0;  z1 = rs1 * ih1;
            rzp = pr;
            s_v[lane] = pk_rtn(z0, z1);              // republish
            asm volatile("" ::: "memory");
        }
        const float dku0 = dk0 * umax, dku1 = dk1 * umax;   // unscale

        // ---- damping / bookkeeping (exact reference logic, fp32) ----
        float gp = fmaxf(fabsf(dku0 / xv0), fabsf(dku1 / xv1));
        float sp = fmaf(dku0, u0, dku1 * u1);
        WMAX(gp); WSUM(sp);
        const float gk     = (lk <= FLc) ? 0.0f : gp;
        const float lk_new = sqrtf(fmaxf(sp, 0.0f));
        const float damp   = 1.0f / (1.0f + gk);
        xv0 -= dku0 * damp;
        xv1 -= dku1 * damp;
        // ---- qx recurrence: Qh*dku = u - umax*rs - ex.*dku (CG invariant) ----
        qx0 -= damp * (u0 - umax * rs0 - ex0 * dku0);
        qx1 -= damp * (u1 - umax * rs1 - ex1 * dku1);
        lk = lk_new;
        if (lk_new < 1e-4f) break;     // remaining motion <= 1e-4 -> out ~4e-6
    }

    // ---- normalize: x / (sum|x| + 1e-8) ----
    float sab = fabsf(xv0) + fabsf(xv1);
    WSUM(sab);
    const float inv = 1.0f / (sab + 1e-8f);
    ((float2*)(out + (size_t)b * NDIM))[lane] = make_float2(xv0 * inv, xv1 * inv);
}

extern "C" void kernel_launch(void* const* d_in, const int* in_sizes, int n_in,
                              void* d_out, int out_size, void* d_ws, size_t ws_size,
                              hipStream_t stream) {
    const float* Q = (const float*)d_in[0];
    const float* R = (const float*)d_in[1];
    float* out     = (float*)d_out;
    const int B    = in_sizes[1] / NDIM;   // 4096
    rpth_kernel<<<dim3(B), dim3(64), 0, stream>>>(Q, R, out);
}